// Round 3
// baseline (148.756 us; speedup 1.0000x reference)
//
#include <hip/hip_runtime.h>

// out[b,g] = sum_f x[b, 3g+f] * w[3g+f] + bias[g]
// B=4096, G=9229, F=3, fp32. Memory-bound: 453.6 MB read + 151.2 MB write.
//
// Structure: 10 gene-tiles x 205 row-groups. Each thread owns 4 fixed genes
// (t + 256j within its tile) -> weights/bias live in registers for the whole
// block. Per row, the x-slice (3*923 floats) is staged to LDS via aligned,
// fully-coalesced float4 loads; compute reads LDS at lane-stride 3 floats
// (banks 3l mod 32 -> conflict-free); stores are lane-contiguous dwords.

#define G       9229
#define GF      (9229 * 3)       // 27687 floats per row
#define B       4096
#define GT      923              // genes per tile (9 x 923 + 1 x 922)
#define NT      10
#define BLK     256
#define RPB     20               // rows per block
#define RGROUPS 205              // 205 * 20 >= 4096
#define STAGE_F4 694             // ceil((3 + 3*923 + 3)/4) float4s

__global__ __launch_bounds__(BLK) void diag_layer_kernel(
    const float* __restrict__ x,
    const float* __restrict__ w,
    const float* __restrict__ bias,
    float* __restrict__ out) {

    __shared__ float lds[STAGE_F4 * 4];   // 11.1 KB

    const int t    = threadIdx.x;
    const int tile = (int)blockIdx.x % NT;
    const int rg   = (int)blockIdx.x / NT;
    const int g0   = tile * GT;
    const int gtloc = min(GT, G - g0);    // 923 or 922

    // Hoist this thread's weights & bias into registers (once per block).
    float wreg[4][3];
    float breg[4];
#pragma unroll
    for (int j = 0; j < 4; ++j) {
        const int gl = t + BLK * j;
        const int gc = g0 + ((gl < gtloc) ? gl : 0);   // clamp: value unused if OOB
        wreg[j][0] = w[3 * gc];
        wreg[j][1] = w[3 * gc + 1];
        wreg[j][2] = w[3 * gc + 2];
        breg[j]    = bias[gc];
    }

    const unsigned x_f4_max = (unsigned)B * (unsigned)GF / 4u - 1u;  // last valid float4

    const int row_begin = rg * RPB;
    const int row_end   = min(row_begin + RPB, B);

    for (int b = row_begin; b < row_end; ++b) {
        const unsigned row_off  = (unsigned)b * (unsigned)GF + (unsigned)(3 * g0);
        const unsigned abase_f4 = row_off >> 2;   // aligned float4 base
        const unsigned shift    = row_off & 3u;

        __syncthreads();   // previous iteration's LDS reads complete
#pragma unroll
        for (int j = 0; j < 3; ++j) {
            const int idx = t + BLK * j;
            if (idx < STAGE_F4) {
                unsigned gi = abase_f4 + (unsigned)idx;
                gi = (gi > x_f4_max) ? x_f4_max : gi;   // clamp tail OOB (unused values)
                reinterpret_cast<float4*>(lds)[idx] =
                    reinterpret_cast<const float4*>(x)[gi];
            }
        }
        __syncthreads();   // staging visible

        const unsigned ob = (unsigned)b * (unsigned)G + (unsigned)g0;
#pragma unroll
        for (int j = 0; j < 4; ++j) {
            const int gl = t + BLK * j;
            if (gl < gtloc) {
                const float* xp = lds + shift + 3 * gl;
                const float r = fmaf(xp[0], wreg[j][0],
                                fmaf(xp[1], wreg[j][1],
                                fmaf(xp[2], wreg[j][2], breg[j])));
                out[ob + (unsigned)gl] = r;
            }
        }
    }
}

extern "C" void kernel_launch(void* const* d_in, const int* in_sizes, int n_in,
                              void* d_out, int out_size, void* d_ws, size_t ws_size,
                              hipStream_t stream) {
    const float* x    = (const float*)d_in[0];
    const float* w    = (const float*)d_in[1];
    const float* bias = (const float*)d_in[2];
    float* out        = (float*)d_out;

    diag_layer_kernel<<<NT * RGROUPS, BLK, 0, stream>>>(x, w, bias, out);
}

// Round 4
// 146.849 us; speedup vs baseline: 1.0130x; 1.0130x over previous
//
#include <hip/hip_runtime.h>

// out[b,g] = sum_f x[b,3g+f] * w[3g+f] + bias[g];  B=4096, G=9229, F=3, fp32.
// Memory-bound: 453.6 MB read + 151.2 MB write.
//
// Each thread owns a fixed 4-gene block -> its 12 weights + 4 biases are
// loaded ONCE into registers (R0 re-loaded them per item: 16 scalar VMEM
// ops per 4 outputs -> request-pipe bound). Row loop is then 3 x-float4
// loads (contiguous 3072B span per wave) + 1 perfectly-coalesced float4
// store per row. No LDS, no barriers (R1's staging regressed: 148.8us).

#define G    9229
#define GF   27687            // 3*G floats per row
#define B    4096
#define GB   2308             // ceil(G/4) gene-blocks; last has 1 gene
#define BLK  256
#define GBG  10               // ceil(GB/BLK) gene-block groups
#define RPC  16               // rows per chunk
#define NRC  (B / RPC)        // 256  -> grid = 2560 = exactly 10 blocks/CU

__global__ __launch_bounds__(BLK) void diag_layer_kernel(
    const float* __restrict__ x,
    const float* __restrict__ w,
    const float* __restrict__ bias,
    float* __restrict__ out) {

    const int t   = threadIdx.x;
    const int gbg = (int)blockIdx.x % GBG;
    const int rc  = (int)blockIdx.x / GBG;
    const int gb  = gbg * BLK + t;
    if (gb >= GB) return;

    const int row0 = rc * RPC;

    if (gb < GB - 1) {
        // Full 4-gene block: hoist 12 weights + 4 biases (aligned float4s).
        const float4 w0 = *reinterpret_cast<const float4*>(w + 12 * gb);
        const float4 w1 = *reinterpret_cast<const float4*>(w + 12 * gb + 4);
        const float4 w2 = *reinterpret_cast<const float4*>(w + 12 * gb + 8);
        const float4 bv = *reinterpret_cast<const float4*>(bias + 4 * gb);

#pragma unroll 4
        for (int r = 0; r < RPC; ++r) {
            const unsigned b  = (unsigned)(row0 + r);
            const unsigned xb = b * (unsigned)GF + 12u * (unsigned)gb;
            const float4 v0 = *reinterpret_cast<const float4*>(x + xb);
            const float4 v1 = *reinterpret_cast<const float4*>(x + xb + 4);
            const float4 v2 = *reinterpret_cast<const float4*>(x + xb + 8);
            float4 o;
            o.x = fmaf(v0.x, w0.x, fmaf(v0.y, w0.y, fmaf(v0.z, w0.z, bv.x)));
            o.y = fmaf(v0.w, w0.w, fmaf(v1.x, w1.x, fmaf(v1.y, w1.y, bv.y)));
            o.z = fmaf(v1.z, w1.z, fmaf(v1.w, w1.w, fmaf(v2.x, w2.x, bv.z)));
            o.w = fmaf(v2.y, w2.y, fmaf(v2.z, w2.z, fmaf(v2.w, w2.w, bv.w)));
            *reinterpret_cast<float4*>(out + (size_t)b * G + 4u * (unsigned)gb) = o;
        }
    } else {
        // gb == GB-1: single tail gene g = 9228 (scalar, avoids OOB vectors).
        const float wa = w[3 * (G - 1)];
        const float wb_ = w[3 * (G - 1) + 1];
        const float wc = w[3 * (G - 1) + 2];
        const float bz = bias[G - 1];
        for (int r = 0; r < RPC; ++r) {
            const unsigned b  = (unsigned)(row0 + r);
            const unsigned xb = b * (unsigned)GF + 3u * (G - 1);
            out[(size_t)b * G + (G - 1)] =
                fmaf(x[xb], wa, fmaf(x[xb + 1], wb_, fmaf(x[xb + 2], wc, bz)));
        }
    }
}

extern "C" void kernel_launch(void* const* d_in, const int* in_sizes, int n_in,
                              void* d_out, int out_size, void* d_ws, size_t ws_size,
                              hipStream_t stream) {
    const float* x    = (const float*)d_in[0];
    const float* w    = (const float*)d_in[1];
    const float* bias = (const float*)d_in[2];
    float* out        = (float*)d_out;

    diag_layer_kernel<<<GBG * NRC, BLK, 0, stream>>>(x, w, bias, out);
}

// Round 5
// 129.545 us; speedup vs baseline: 1.1483x; 1.1336x over previous
//
#include <hip/hip_runtime.h>

// out[b,g] = sum_f x[b,3g+f] * w[3g+f] + bias[g];  B=4096, G=9229, F=3, fp32.
// Memory-bound: 453.6 MB read + 151.2 MB write -> ~96 us floor @ 6.3 TB/s.
//
// R0 (135us): linear streaming but 16 stride-48B w/bias gathers per 256
// outputs -> request-pipe heavy. R3 (147us): hoisted w but grid 2560 =
// 40 waves/CU demanded vs 32 capacity -> straggler tail ~1.25x.
// This version: hoisted-w memory structure + PERFECT balance:
// 10240 uniform units (10 gene-groups x 1024 row-quads), grid 2048
// -> exactly 5 units/block, 8 blocks/CU, no tail. w/bias reloaded once
// per unit (4 loads per 4 rows). Misaligned float4 ok (proven in R3).

#define G     9229
#define GF    27687           // 3*G floats per row
#define B     4096
#define BLK   256
#define GRID  2048            // 8 blocks/CU exactly
#define NUNIT 10240           // 10 gene-groups * 1024 row-quads = GRID*5

__global__ __launch_bounds__(BLK) void diag_layer_kernel(
    const float* __restrict__ x,
    const float* __restrict__ w,
    const float* __restrict__ bias,
    float* __restrict__ out) {

    const int t = threadIdx.x;

    for (int u = (int)blockIdx.x; u < NUNIT; u += GRID) {
        const int gbg  = u >> 10;          // gene-group 0..9
        const int rc   = u & 1023;         // row-quad 0..1023
        const int gb   = gbg * BLK + t;    // gene-block (4 genes)
        const int row0 = rc * 4;

        if (gb < 2307) {
            // Full 4-gene block: 12 weights + 4 biases in registers.
            const float4 w0 = *reinterpret_cast<const float4*>(w + 12 * gb);
            const float4 w1 = *reinterpret_cast<const float4*>(w + 12 * gb + 4);
            const float4 w2 = *reinterpret_cast<const float4*>(w + 12 * gb + 8);
            const float4 bv = *reinterpret_cast<const float4*>(bias + 4 * gb);

#pragma unroll
            for (int r = 0; r < 4; ++r) {
                const unsigned b  = (unsigned)(row0 + r);
                const unsigned xb = b * (unsigned)GF + 12u * (unsigned)gb;
                const float4 v0 = *reinterpret_cast<const float4*>(x + xb);
                const float4 v1 = *reinterpret_cast<const float4*>(x + xb + 4);
                const float4 v2 = *reinterpret_cast<const float4*>(x + xb + 8);
                float4 o;
                o.x = fmaf(v0.x, w0.x, fmaf(v0.y, w0.y, fmaf(v0.z, w0.z, bv.x)));
                o.y = fmaf(v0.w, w0.w, fmaf(v1.x, w1.x, fmaf(v1.y, w1.y, bv.y)));
                o.z = fmaf(v1.z, w1.z, fmaf(v1.w, w1.w, fmaf(v2.x, w2.x, bv.z)));
                o.w = fmaf(v2.y, w2.y, fmaf(v2.z, w2.z, fmaf(v2.w, w2.w, bv.w)));
                *reinterpret_cast<float4*>(out + b * (unsigned)G + 4u * (unsigned)gb) = o;
            }
        } else if (gb == 2307) {
            // Tail gene 9228 (G = 4*2307 + 1): scalar path.
            const float wa = w[3 * (G - 1)];
            const float wb_ = w[3 * (G - 1) + 1];
            const float wc = w[3 * (G - 1) + 2];
            const float bz = bias[G - 1];
#pragma unroll
            for (int r = 0; r < 4; ++r) {
                const unsigned b  = (unsigned)(row0 + r);
                const unsigned xb = b * (unsigned)GF + 3u * (G - 1);
                out[b * (unsigned)G + (G - 1)] =
                    fmaf(x[xb], wa, fmaf(x[xb + 1], wb_, fmaf(x[xb + 2], wc, bz)));
            }
        }
        // gb > 2307: no work this unit (lanes idle only in gene-group 9).
    }
}

extern "C" void kernel_launch(void* const* d_in, const int* in_sizes, int n_in,
                              void* d_out, int out_size, void* d_ws, size_t ws_size,
                              hipStream_t stream) {
    const float* x    = (const float*)d_in[0];
    const float* w    = (const float*)d_in[1];
    const float* bias = (const float*)d_in[2];
    float* out        = (float*)d_out;

    diag_layer_kernel<<<GRID, BLK, 0, stream>>>(x, w, bias, out);
}

// Round 6
// 125.884 us; speedup vs baseline: 1.1817x; 1.0291x over previous
//
#include <hip/hip_runtime.h>

// out[b,g] = sum_f x[b,3g+f]*w[3g+f] + bias[g];  B=4096, G=9229, F=3, fp32.
//
// Fully wave-contiguous streaming: lanes read x as a pure float4 stream
// (payload == span, no 48B-stride line amplification), reassemble the
// stride-3 dot-products in-register with wave shuffles, transpose outputs
// via 4 pull-shuffles so stores are contiguous float4 too. No LDS/barriers.
//
// Window = 256 genes = 768 floats = 192 f4 = 3 slots x 64 lanes.
// f4 j (lane j%64, slot j/64), m = j%3 = (slot+lane)%3  [64 = 1 mod 3]:
//   m=0: gene 4k   = p0+p1+p2         ; gene 4k+1 = p3 + next(p0+p1)
//   m=1: gene 4k+2 = p2+p3 + next(p0) ; [sends p0+p1 to pred]
//   m=2: gene 4k+3 = p1+p2+p3         ; [sends p0 to pred]
// Ring-exchange: E[s] = shfl(send[s], t+1); lane63 uses E[s+1] (slot wrap).
// Lane63/slot2 (j=191) consumes nothing: 256 genes end exactly at f4 192.
// Output transpose: receiver t pulls genes 4t..4t+3 from lanes (3t+i)&63
// (CRT: j=3t+i is the unique f4 with j%3==i, j%64==(3t+i)%64).

#define G     9229
#define GF    27687
#define NB    4096
#define NWIN  36          // full 256-gene windows (genes 0..9215)
#define SLOTS 221         // wave-columns per window; 37*221 = 8177 <= 8192
#define NW    (37 * SLOTS)

__global__ __launch_bounds__(256) void diag_layer_kernel(
    const float* __restrict__ x,
    const float* __restrict__ w,
    const float* __restrict__ bias,
    float* __restrict__ out) {

    const int t = (int)(threadIdx.x & 63);
    const int W = (int)blockIdx.x * 4 + (int)(threadIdx.x >> 6);
    if (W >= NW) return;
    const int win = W % 37;
    const int s   = W / 37;

    if (win < NWIN) {
        const int F0 = 768 * win;      // window float base within a row
        // Hoisted weights / bias (aligned float4s, L2-resident).
        const float4 w0 = *reinterpret_cast<const float4*>(w + F0 + 4 * t);
        const float4 w1 = *reinterpret_cast<const float4*>(w + F0 + 256 + 4 * t);
        const float4 w2 = *reinterpret_cast<const float4*>(w + F0 + 512 + 4 * t);
        const float4 bv = *reinterpret_cast<const float4*>(bias + 256 * win + 4 * t);

        const int tm   = t % 3;
        const bool last = (t == 63);
        const int srcA = (3 * t) & 63;
        const int srcC = (3 * t + 1) & 63;
        const int srcD = (3 * t + 2) & 63;

#pragma unroll 2
        for (int r = s; r < NB; r += SLOTS) {
            const float* xr = x + r * GF + F0;
            const float4 v0 = *reinterpret_cast<const float4*>(xr + 4 * t);
            const float4 v1 = *reinterpret_cast<const float4*>(xr + 256 + 4 * t);
            const float4 v2 = *reinterpret_cast<const float4*>(xr + 512 + 4 * t);

            // slot 0 products/partials
            const float a0 = v0.x * w0.x, a1 = v0.y * w0.y, a2 = v0.z * w0.z, a3 = v0.w * w0.w;
            const float q01_0 = a0 + a1, q23_0 = a2 + a3;
            const float q012_0 = q01_0 + a2, q123_0 = q23_0 + a1;
            // slot 1
            const float b0 = v1.x * w1.x, b1 = v1.y * w1.y, b2 = v1.z * w1.z, b3 = v1.w * w1.w;
            const float q01_1 = b0 + b1, q23_1 = b2 + b3;
            const float q012_1 = q01_1 + b2, q123_1 = q23_1 + b1;
            // slot 2
            const float c0 = v2.x * w2.x, c1 = v2.y * w2.y, c2 = v2.z * w2.z, c3 = v2.w * w2.w;
            const float q01_2 = c0 + c1, q23_2 = c2 + c3;
            const float q012_2 = q01_2 + c2, q123_2 = q23_2 + c1;

            // sends: what my predecessor (f4 j-1) needs from me:
            //   if my m==1 -> p0+p1 ; if my m==2 -> p0  (m==0: unused)
            const float s0 = (tm == 1) ? q01_0 : a0;
            const float s1 = (tm == 0) ? q01_1 : b0;
            const float s2 = (tm == 2) ? q01_2 : c0;
            const float r0 = __shfl(s0, (t + 1) & 63);
            const float r1 = __shfl(s1, (t + 1) & 63);
            const float r2 = __shfl(s2, (t + 1) & 63);
            const float E0 = last ? r1 : r0;   // lane63: wrap into next slot
            const float E1 = last ? r2 : r1;
            const float E2 = r2;               // lane63/slot2 never consumes

            const float bb0 = a3 + E0, bb1 = b3 + E1, bb2 = c3 + E2;
            const float cc0 = q23_0 + E0, cc1 = q23_1 + E1, cc2 = q23_2 + E2;

            // per-lane selected outputs (one slot each of m=0,1,2)
            const float A = (tm == 0) ? q012_0 : (tm == 2) ? q012_1 : q012_2;
            const float Bv = (tm == 0) ? bb0   : (tm == 2) ? bb1   : bb2;
            const float C = (tm == 1) ? cc0   : (tm == 0) ? cc1   : cc2;
            const float D = (tm == 2) ? q123_0 : (tm == 1) ? q123_1 : q123_2;

            // output transpose: lane t collects genes 4t..4t+3 of the window
            float4 o;
            o.x = __shfl(A,  srcA) + bv.x;
            o.y = __shfl(Bv, srcA) + bv.y;
            o.z = __shfl(C,  srcC) + bv.z;
            o.w = __shfl(D,  srcD) + bv.w;

            *reinterpret_cast<float4*>(out + r * G + 256 * win + 4 * t) = o;
        }
    } else {
        // Tail window: genes 9216..9228 (13 genes), scalar path.
        if (t < 13) {
            const int g = 9216 + t;
            const float wa = w[3 * g], wb = w[3 * g + 1], wc = w[3 * g + 2];
            const float bz = bias[g];
            for (int r = s; r < NB; r += SLOTS) {
                const float* xr = x + r * GF + 3 * g;
                out[r * G + g] =
                    fmaf(xr[0], wa, fmaf(xr[1], wb, fmaf(xr[2], wc, bz)));
            }
        }
    }
}

extern "C" void kernel_launch(void* const* d_in, const int* in_sizes, int n_in,
                              void* d_out, int out_size, void* d_ws, size_t ws_size,
                              hipStream_t stream) {
    const float* x    = (const float*)d_in[0];
    const float* w    = (const float*)d_in[1];
    const float* bias = (const float*)d_in[2];
    float* out        = (float*)d_out;

    diag_layer_kernel<<<2048, 256, 0, stream>>>(x, w, bias, out);
}

// Round 7
// 120.615 us; speedup vs baseline: 1.2333x; 1.0437x over previous
//
#include <hip/hip_runtime.h>

// out[b,g] = sum_f x[b,3g+f]*w[3g+f] + bias[g];  B=4096, G=9229, F=3, fp32.
//
// R5 structure (wave-contiguous float4 streams, in-register shuffle
// reassembly, contiguous float4 stores) + NON-TEMPORAL loads/stores on the
// streaming data (x, out). x: 454 MB zero-reuse; out: 151 MB zero-reuse;
// both thrash the 32 MB L2 if allowed to allocate. w/bias (144 KB, reused
// by all waves) stay on the cached path.
//
// Window = 256 genes = 768 floats = 192 f4 = 3 slots x 64 lanes.
// f4 j (lane j%64, slot j/64), m = j%3 = (slot+lane)%3  [64 = 1 mod 3]:
//   m=0: gene 4k   = p0+p1+p2         ; gene 4k+1 = p3 + next(p0+p1)
//   m=1: gene 4k+2 = p2+p3 + next(p0) ; [sends p0+p1 to pred]
//   m=2: gene 4k+3 = p1+p2+p3         ; [sends p0 to pred]
// Ring-exchange: E[s] = shfl(send[s], t+1); lane63 uses E[s+1] (slot wrap).
// Output transpose: lane t pulls genes 4t..4t+3 from lanes (3t+i)&63 (CRT).

#define G     9229
#define GF    27687
#define NB    4096
#define NWIN  36          // full 256-gene windows (genes 0..9215)
#define SLOTS 221         // wave-columns per window; 37*221 = 8177 <= 8192
#define NW    (37 * SLOTS)

typedef float f32x4 __attribute__((ext_vector_type(4)));

__global__ __launch_bounds__(256) void diag_layer_kernel(
    const float* __restrict__ x,
    const float* __restrict__ w,
    const float* __restrict__ bias,
    float* __restrict__ out) {

    const int t = (int)(threadIdx.x & 63);
    const int W = (int)blockIdx.x * 4 + (int)(threadIdx.x >> 6);
    if (W >= NW) return;
    const int win = W % 37;
    const int s   = W / 37;

    if (win < NWIN) {
        const int F0 = 768 * win;      // window float base within a row
        // Hoisted weights / bias (aligned float4s, L2-resident, CACHED).
        const float4 w0 = *reinterpret_cast<const float4*>(w + F0 + 4 * t);
        const float4 w1 = *reinterpret_cast<const float4*>(w + F0 + 256 + 4 * t);
        const float4 w2 = *reinterpret_cast<const float4*>(w + F0 + 512 + 4 * t);
        const float4 bv = *reinterpret_cast<const float4*>(bias + 256 * win + 4 * t);

        const int tm   = t % 3;
        const bool last = (t == 63);
        const int srcA = (3 * t) & 63;
        const int srcC = (3 * t + 1) & 63;
        const int srcD = (3 * t + 2) & 63;

#pragma unroll 2
        for (int r = s; r < NB; r += SLOTS) {
            const float* xr = x + r * GF + F0;
            const f32x4 v0 = __builtin_nontemporal_load(
                reinterpret_cast<const f32x4*>(xr + 4 * t));
            const f32x4 v1 = __builtin_nontemporal_load(
                reinterpret_cast<const f32x4*>(xr + 256 + 4 * t));
            const f32x4 v2 = __builtin_nontemporal_load(
                reinterpret_cast<const f32x4*>(xr + 512 + 4 * t));

            // slot 0 products/partials
            const float a0 = v0.x * w0.x, a1 = v0.y * w0.y, a2 = v0.z * w0.z, a3 = v0.w * w0.w;
            const float q01_0 = a0 + a1, q23_0 = a2 + a3;
            const float q012_0 = q01_0 + a2, q123_0 = q23_0 + a1;
            // slot 1
            const float b0 = v1.x * w1.x, b1 = v1.y * w1.y, b2 = v1.z * w1.z, b3 = v1.w * w1.w;
            const float q01_1 = b0 + b1, q23_1 = b2 + b3;
            const float q012_1 = q01_1 + b2, q123_1 = q23_1 + b1;
            // slot 2
            const float c0 = v2.x * w2.x, c1 = v2.y * w2.y, c2 = v2.z * w2.z, c3 = v2.w * w2.w;
            const float q01_2 = c0 + c1, q23_2 = c2 + c3;
            const float q012_2 = q01_2 + c2, q123_2 = q23_2 + c1;

            // sends: pred (f4 j-1) needs: m==1 -> p0+p1 ; m==2 -> p0
            const float s0 = (tm == 1) ? q01_0 : a0;
            const float s1 = (tm == 0) ? q01_1 : b0;
            const float s2 = (tm == 2) ? q01_2 : c0;
            const float r0 = __shfl(s0, (t + 1) & 63);
            const float r1 = __shfl(s1, (t + 1) & 63);
            const float r2 = __shfl(s2, (t + 1) & 63);
            const float E0 = last ? r1 : r0;   // lane63: wrap into next slot
            const float E1 = last ? r2 : r1;
            const float E2 = r2;               // lane63/slot2 never consumes

            const float bb0 = a3 + E0, bb1 = b3 + E1, bb2 = c3 + E2;
            const float cc0 = q23_0 + E0, cc1 = q23_1 + E1, cc2 = q23_2 + E2;

            // per-lane selected outputs (one slot each of m=0,1,2)
            const float A  = (tm == 0) ? q012_0 : (tm == 2) ? q012_1 : q012_2;
            const float Bv = (tm == 0) ? bb0   : (tm == 2) ? bb1   : bb2;
            const float C  = (tm == 1) ? cc0   : (tm == 0) ? cc1   : cc2;
            const float D  = (tm == 2) ? q123_0 : (tm == 1) ? q123_1 : q123_2;

            // output transpose: lane t collects genes 4t..4t+3 of the window
            f32x4 o;
            o.x = __shfl(A,  srcA) + bv.x;
            o.y = __shfl(Bv, srcA) + bv.y;
            o.z = __shfl(C,  srcC) + bv.z;
            o.w = __shfl(D,  srcD) + bv.w;

            __builtin_nontemporal_store(
                o, reinterpret_cast<f32x4*>(out + r * G + 256 * win + 4 * t));
        }
    } else {
        // Tail window: genes 9216..9228 (13 genes), scalar path.
        if (t < 13) {
            const int g = 9216 + t;
            const float wa = w[3 * g], wb = w[3 * g + 1], wc = w[3 * g + 2];
            const float bz = bias[g];
            for (int r = s; r < NB; r += SLOTS) {
                const float* xr = x + r * GF + 3 * g;
                out[r * G + g] =
                    fmaf(xr[0], wa, fmaf(xr[1], wb, fmaf(xr[2], wc, bz)));
            }
        }
    }
}

extern "C" void kernel_launch(void* const* d_in, const int* in_sizes, int n_in,
                              void* d_out, int out_size, void* d_ws, size_t ws_size,
                              hipStream_t stream) {
    const float* x    = (const float*)d_in[0];
    const float* w    = (const float*)d_in[1];
    const float* bias = (const float*)d_in[2];
    float* out        = (float*)d_out;

    diag_layer_kernel<<<2048, 256, 0, stream>>>(x, w, bias, out);
}

// Round 8
// 119.000 us; speedup vs baseline: 1.2500x; 1.0136x over previous
//
#include <hip/hip_runtime.h>

// out[b,g] = sum_f x[b,3g+f]*w[3g+f] + bias[g];  B=4096, G=9229, F=3, fp32.
//
// Flat decomposition: output i = b*G+g  <->  x floats 3i..3i+2 (seamless
// across row boundaries). Unit = 256 consecutive outputs = 192 x-f4s,
// PERFECTLY 16B-ALIGNED and contiguous for both the x read stream and the
// out write stream (R5/R6's per-row windows were misaligned for 3/4 of
// rows -> partial-sector NT writes + extra line lookups).
// Weight wrap at gene G handled by wrap-extended copies in d_ws:
//   wext[27687+768], bext[9229+256]  (built by a setup kernel each launch).
// In-register shuffle reassembly identical to R6 (768u = 0 mod 3 keeps
// unit starts on gene boundaries):
//   f4 j (slot s=j/64, lane t=j%64), m=(s+t)%3:
//   m=0: gene4k=p0+p1+p2; gene4k+1=p3+next(p0+p1)
//   m=1: gene4k+2=p2+p3+next(p0); m=2: gene4k+3=p1+p2+p3
//   ring shfl(t+1) with lane63 slot-wrap; output transpose via 4 pull-shfls.
// 147664 units total (exact, no tail). NT on x/out; w/bias cached.

#define G       9229
#define GFW     27687            // 3*G
#define NUNIT   147664           // 37,801,984 / 256
#define NWAVES  8192             // grid 2048 x 4 waves
#define WEXT_N  (GFW + 768)      // 28455
#define BEXT_OFF 28456           // float offset of bext in ws (16B aligned)
#define BEXT_N  (G + 256)        // 9485
#define WS_FLOATS (BEXT_OFF + BEXT_N)   // 37941 -> 151764 bytes

typedef float f32x4 __attribute__((ext_vector_type(4)));

__global__ __launch_bounds__(256) void build_ext_kernel(
    const float* __restrict__ w, const float* __restrict__ bias,
    float* __restrict__ ws) {
    const int i = (int)blockIdx.x * 256 + (int)threadIdx.x;
    if (i < WEXT_N) {
        ws[i] = w[i >= GFW ? i - GFW : i];
    } else {
        const int k = i - WEXT_N;
        if (k < BEXT_N) ws[BEXT_OFF + k] = bias[k >= G ? k - G : k];
    }
}

__global__ __launch_bounds__(256, 8) void diag_flat_kernel(
    const float* __restrict__ x,
    const float* __restrict__ ws,
    float* __restrict__ out) {

    const float* wext = ws;
    const float* bext = ws + BEXT_OFF;

    const int t  = (int)(threadIdx.x & 63);
    const int wv = (int)blockIdx.x * 4 + (int)(threadIdx.x >> 6);

    const int tm    = t % 3;
    const bool last = (t == 63);
    const int srcA = (3 * t) & 63;
    const int srcC = (3 * t + 1) & 63;
    const int srcD = (3 * t + 2) & 63;

    for (unsigned u = (unsigned)wv; u < NUNIT; u += NWAVES) {
        const unsigned O0  = 256u * u;          // first output of unit
        const unsigned g0  = O0 % (unsigned)G;  // gene of first output
        const unsigned wf0 = 3u * g0;           // weight float base (wrap-free in wext)
        const float* xr = x + 768u * u;         // 16B-aligned

        const f32x4 v0 = __builtin_nontemporal_load(
            reinterpret_cast<const f32x4*>(xr + 4 * t));
        const f32x4 v1 = __builtin_nontemporal_load(
            reinterpret_cast<const f32x4*>(xr + 256 + 4 * t));
        const f32x4 v2 = __builtin_nontemporal_load(
            reinterpret_cast<const f32x4*>(xr + 512 + 4 * t));

        // cached, dword-aligned (16B-misaligned ok), L1/L2-resident
        const float4 w0 = *reinterpret_cast<const float4*>(wext + wf0 + 4 * t);
        const float4 w1 = *reinterpret_cast<const float4*>(wext + wf0 + 256 + 4 * t);
        const float4 w2 = *reinterpret_cast<const float4*>(wext + wf0 + 512 + 4 * t);
        const float4 bv = *reinterpret_cast<const float4*>(bext + g0 + 4 * t);

        // slot products / partials
        const float a0 = v0.x * w0.x, a1 = v0.y * w0.y, a2 = v0.z * w0.z, a3 = v0.w * w0.w;
        const float q01_0 = a0 + a1, q23_0 = a2 + a3;
        const float q012_0 = q01_0 + a2, q123_0 = q23_0 + a1;
        const float b0 = v1.x * w1.x, b1 = v1.y * w1.y, b2 = v1.z * w1.z, b3 = v1.w * w1.w;
        const float q01_1 = b0 + b1, q23_1 = b2 + b3;
        const float q012_1 = q01_1 + b2, q123_1 = q23_1 + b1;
        const float c0 = v2.x * w2.x, c1 = v2.y * w2.y, c2 = v2.z * w2.z, c3 = v2.w * w2.w;
        const float q01_2 = c0 + c1, q23_2 = c2 + c3;
        const float q012_2 = q01_2 + c2, q123_2 = q23_2 + c1;

        // ring exchange: pred (f4 j-1) needs: m==1 -> p0+p1 ; m==2 -> p0
        const float s0 = (tm == 1) ? q01_0 : a0;
        const float s1 = (tm == 0) ? q01_1 : b0;
        const float s2 = (tm == 2) ? q01_2 : c0;
        const float r0 = __shfl(s0, (t + 1) & 63);
        const float r1 = __shfl(s1, (t + 1) & 63);
        const float r2 = __shfl(s2, (t + 1) & 63);
        const float E0 = last ? r1 : r0;
        const float E1 = last ? r2 : r1;
        const float E2 = r2;

        const float bb0 = a3 + E0, bb1 = b3 + E1, bb2 = c3 + E2;
        const float cc0 = q23_0 + E0, cc1 = q23_1 + E1, cc2 = q23_2 + E2;

        const float A  = (tm == 0) ? q012_0 : (tm == 2) ? q012_1 : q012_2;
        const float Bv = (tm == 0) ? bb0   : (tm == 2) ? bb1   : bb2;
        const float C  = (tm == 1) ? cc0   : (tm == 0) ? cc1   : cc2;
        const float D  = (tm == 2) ? q123_0 : (tm == 1) ? q123_1 : q123_2;

        f32x4 o;
        o.x = __shfl(A,  srcA) + bv.x;
        o.y = __shfl(Bv, srcA) + bv.y;
        o.z = __shfl(C,  srcC) + bv.z;
        o.w = __shfl(D,  srcD) + bv.w;

        __builtin_nontemporal_store(
            o, reinterpret_cast<f32x4*>(out + O0 + 4 * t));   // 16B-aligned
    }
}

// ---------------- fallback (R6 kernel) for small ws_size ----------------
#define NB    4096
#define NWIN  36
#define SLOTS 221
#define NWF   (37 * SLOTS)

__global__ __launch_bounds__(256) void diag_layer_kernel_fb(
    const float* __restrict__ x, const float* __restrict__ w,
    const float* __restrict__ bias, float* __restrict__ out) {
    const int t = (int)(threadIdx.x & 63);
    const int W = (int)blockIdx.x * 4 + (int)(threadIdx.x >> 6);
    if (W >= NWF) return;
    const int win = W % 37;
    const int s   = W / 37;
    if (win < NWIN) {
        const int F0 = 768 * win;
        const float4 w0 = *reinterpret_cast<const float4*>(w + F0 + 4 * t);
        const float4 w1 = *reinterpret_cast<const float4*>(w + F0 + 256 + 4 * t);
        const float4 w2 = *reinterpret_cast<const float4*>(w + F0 + 512 + 4 * t);
        const float4 bv = *reinterpret_cast<const float4*>(bias + 256 * win + 4 * t);
        const int tm = t % 3;
        const bool last = (t == 63);
        const int srcA = (3 * t) & 63, srcC = (3 * t + 1) & 63, srcD = (3 * t + 2) & 63;
#pragma unroll 2
        for (int r = s; r < NB; r += SLOTS) {
            const float* xr = x + r * GFW + F0;
            const f32x4 v0 = __builtin_nontemporal_load(reinterpret_cast<const f32x4*>(xr + 4 * t));
            const f32x4 v1 = __builtin_nontemporal_load(reinterpret_cast<const f32x4*>(xr + 256 + 4 * t));
            const f32x4 v2 = __builtin_nontemporal_load(reinterpret_cast<const f32x4*>(xr + 512 + 4 * t));
            const float a0 = v0.x * w0.x, a1 = v0.y * w0.y, a2 = v0.z * w0.z, a3 = v0.w * w0.w;
            const float q01_0 = a0 + a1, q23_0 = a2 + a3, q012_0 = a0 + a1 + a2, q123_0 = q23_0 + a1;
            const float b0 = v1.x * w1.x, b1 = v1.y * w1.y, b2 = v1.z * w1.z, b3 = v1.w * w1.w;
            const float q01_1 = b0 + b1, q23_1 = b2 + b3, q012_1 = q01_1 + b2, q123_1 = q23_1 + b1;
            const float c0 = v2.x * w2.x, c1 = v2.y * w2.y, c2 = v2.z * w2.z, c3 = v2.w * w2.w;
            const float q01_2 = c0 + c1, q23_2 = c2 + c3, q012_2 = q01_2 + c2, q123_2 = q23_2 + c1;
            const float s0 = (tm == 1) ? q01_0 : a0;
            const float s1 = (tm == 0) ? q01_1 : b0;
            const float s2 = (tm == 2) ? q01_2 : c0;
            const float r0 = __shfl(s0, (t + 1) & 63);
            const float r1 = __shfl(s1, (t + 1) & 63);
            const float r2 = __shfl(s2, (t + 1) & 63);
            const float E0 = last ? r1 : r0, E1 = last ? r2 : r1, E2 = r2;
            const float bb0 = a3 + E0, bb1 = b3 + E1, bb2 = c3 + E2;
            const float cc0 = q23_0 + E0, cc1 = q23_1 + E1, cc2 = q23_2 + E2;
            const float A  = (tm == 0) ? q012_0 : (tm == 2) ? q012_1 : q012_2;
            const float Bv = (tm == 0) ? bb0 : (tm == 2) ? bb1 : bb2;
            const float C  = (tm == 1) ? cc0 : (tm == 0) ? cc1 : cc2;
            const float D  = (tm == 2) ? q123_0 : (tm == 1) ? q123_1 : q123_2;
            f32x4 o;
            o.x = __shfl(A, srcA) + bv.x;
            o.y = __shfl(Bv, srcA) + bv.y;
            o.z = __shfl(C, srcC) + bv.z;
            o.w = __shfl(D, srcD) + bv.w;
            __builtin_nontemporal_store(o, reinterpret_cast<f32x4*>(out + r * G + 256 * win + 4 * t));
        }
    } else if (t < 13) {
        const int g = 9216 + t;
        const float wa = w[3 * g], wb = w[3 * g + 1], wc = w[3 * g + 2];
        const float bz = bias[g];
        for (int r = s; r < NB; r += SLOTS) {
            const float* xr = x + r * GFW + 3 * g;
            out[r * G + g] = fmaf(xr[0], wa, fmaf(xr[1], wb, fmaf(xr[2], wc, bz)));
        }
    }
}

extern "C" void kernel_launch(void* const* d_in, const int* in_sizes, int n_in,
                              void* d_out, int out_size, void* d_ws, size_t ws_size,
                              hipStream_t stream) {
    const float* x    = (const float*)d_in[0];
    const float* w    = (const float*)d_in[1];
    const float* bias = (const float*)d_in[2];
    float* out        = (float*)d_out;

    if (ws_size >= WS_FLOATS * sizeof(float)) {
        float* ws = (float*)d_ws;
        build_ext_kernel<<<(WEXT_N + BEXT_N + 255) / 256, 256, 0, stream>>>(w, bias, ws);
        diag_flat_kernel<<<2048, 256, 0, stream>>>(x, ws, out);
    } else {
        diag_layer_kernel_fb<<<2048, 256, 0, stream>>>(x, w, bias, out);
    }
}